// Round 1
// baseline (1189.345 us; speedup 1.0000x reference)
//
#include <hip/hip_runtime.h>
#include <hip/hip_bf16.h>

// Problem constants (from reference): N_NODES=50000, N_EDGES=800000, MAX_NEI=16, D=256
#define D_DIM 256
#define MAX_NEI 16

// ---------------- Kernel 1: support = input @ W^T + b_lin (fp32 GEMM) ----------------
// C[m][o] = sum_d A[m][d] * W[o][d]  (both row-major with contiguous K -> "NT" dot-of-rows)
// Tile: 128x128, TK=32, 256 threads, 8x8 micro-tile per thread.
#define TM 128
#define TN 128
#define TK 32
#define LDS_PAD 4  // row stride 132 floats = 528 B, 16B-aligned for float4 LDS reads

__global__ __launch_bounds__(256) void gemm_support(
    const float* __restrict__ A,     // [M, 256]
    const float* __restrict__ W,     // [256, 256]
    const float* __restrict__ blin,  // [256]
    float* __restrict__ S,           // [M, 256] out
    int M)
{
    __shared__ float As[TK][TM + LDS_PAD];
    __shared__ float Ws[TK][TN + LDS_PAD];

    const int tid = threadIdx.x;
    const int tx = tid & 15;        // col group
    const int ty = tid >> 4;        // row group
    const int m0 = blockIdx.x * TM;
    const int n0 = blockIdx.y * TN;

    // staging mapping: 8 threads cover one row's 32-float K-slab as float4
    const int kk = (tid & 7) * 4;   // k offset within tile
    const int rr = tid >> 3;        // row 0..31, 4 passes of 32

    float acc[8][8];
    #pragma unroll
    for (int i = 0; i < 8; ++i)
        #pragma unroll
        for (int j = 0; j < 8; ++j) acc[i][j] = 0.f;

    for (int k0 = 0; k0 < D_DIM; k0 += TK) {
        // stage A tile (transposed to [k][m])
        #pragma unroll
        for (int p = 0; p < 4; ++p) {
            int m = m0 + rr + 32 * p;
            int ms = m < M ? m : (M - 1);           // clamp; garbage rows masked at store
            const float4 v = *(const float4*)(A + (size_t)ms * D_DIM + k0 + kk);
            As[kk + 0][rr + 32 * p] = v.x;
            As[kk + 1][rr + 32 * p] = v.y;
            As[kk + 2][rr + 32 * p] = v.z;
            As[kk + 3][rr + 32 * p] = v.w;
        }
        // stage W tile (transposed to [k][o]); N=256 so never OOB
        #pragma unroll
        for (int p = 0; p < 4; ++p) {
            int o = n0 + rr + 32 * p;
            const float4 v = *(const float4*)(W + (size_t)o * D_DIM + k0 + kk);
            Ws[kk + 0][rr + 32 * p] = v.x;
            Ws[kk + 1][rr + 32 * p] = v.y;
            Ws[kk + 2][rr + 32 * p] = v.z;
            Ws[kk + 3][rr + 32 * p] = v.w;
        }
        __syncthreads();

        #pragma unroll
        for (int k = 0; k < TK; ++k) {
            float a[8], b[8];
            *(float4*)&a[0] = *(const float4*)&As[k][ty * 8 + 0];
            *(float4*)&a[4] = *(const float4*)&As[k][ty * 8 + 4];
            *(float4*)&b[0] = *(const float4*)&Ws[k][tx * 8 + 0];
            *(float4*)&b[4] = *(const float4*)&Ws[k][tx * 8 + 4];
            #pragma unroll
            for (int i = 0; i < 8; ++i)
                #pragma unroll
                for (int j = 0; j < 8; ++j)
                    acc[i][j] += a[i] * b[j];
        }
        __syncthreads();
    }

    // epilogue: + b_lin, store
    const int oc = n0 + tx * 8;
    float4 b0 = *(const float4*)(blin + oc);
    float4 b1 = *(const float4*)(blin + oc + 4);
    #pragma unroll
    for (int i = 0; i < 8; ++i) {
        int m = m0 + ty * 8 + i;
        if (m < M) {
            float4 v0, v1;
            v0.x = acc[i][0] + b0.x; v0.y = acc[i][1] + b0.y;
            v0.z = acc[i][2] + b0.z; v0.w = acc[i][3] + b0.w;
            v1.x = acc[i][4] + b1.x; v1.y = acc[i][5] + b1.y;
            v1.z = acc[i][6] + b1.z; v1.w = acc[i][7] + b1.w;
            *(float4*)(S + (size_t)m * D_DIM + oc) = v0;
            *(float4*)(S + (size_t)m * D_DIM + oc + 4) = v1;
        }
    }
}

// ---------------- Kernel 2: gather, elementwise multiply, reduce over K, tanh+bias ----------------
// One wave (64 lanes) per node; lane handles float4 -> one 1KB row per vector load, fully coalesced.
__device__ __forceinline__ float fast_tanh(float x) {
    // exactly tanh algebraically: 1 - 2/(e^{2x}+1); overflow-safe at both ends
    float e = __expf(2.0f * x);
    return 1.0f - 2.0f / (e + 1.0f);
}

__global__ __launch_bounds__(256) void gather_msg(
    const float* __restrict__ S,       // [N, 256] support
    const float* __restrict__ fedges,  // [E, 256]
    const int*   __restrict__ a2a,     // [N, 16]
    const int*   __restrict__ n2e,     // [N, 16]
    const float* __restrict__ bias,    // [256]
    float* __restrict__ out,           // [N, 256]
    int N)
{
    const int wave = (int)((blockIdx.x * (size_t)blockDim.x + threadIdx.x) >> 6);
    const int lane = threadIdx.x & 63;
    if (wave >= N) return;

    const int* __restrict__ ia = a2a + (size_t)wave * MAX_NEI;
    const int* __restrict__ ie = n2e + (size_t)wave * MAX_NEI;
    const int off = lane * 4;

    float4 acc = make_float4(0.f, 0.f, 0.f, 0.f);
    #pragma unroll
    for (int k = 0; k < MAX_NEI; ++k) {
        const int na = ia[k];
        const int ne = ie[k];
        const float4 s = *(const float4*)(S + (size_t)na * D_DIM + off);
        const float4 f = *(const float4*)(fedges + (size_t)ne * D_DIM + off);
        acc.x += s.x * f.x;
        acc.y += s.y * f.y;
        acc.z += s.z * f.z;
        acc.w += s.w * f.w;
    }

    const float4 bv = *(const float4*)(bias + off);
    float4 r;
    r.x = fast_tanh(acc.x) + bv.x;
    r.y = fast_tanh(acc.y) + bv.y;
    r.z = fast_tanh(acc.z) + bv.z;
    r.w = fast_tanh(acc.w) + bv.w;
    *(float4*)(out + (size_t)wave * D_DIM + off) = r;
}

extern "C" void kernel_launch(void* const* d_in, const int* in_sizes, int n_in,
                              void* d_out, int out_size, void* d_ws, size_t ws_size,
                              hipStream_t stream) {
    const float* input_features = (const float*)d_in[0];  // [N, 256]
    const float* fedges         = (const float*)d_in[1];  // [E, 256]
    const int*   a2a            = (const int*)d_in[2];    // [N, 16]
    const int*   n2e            = (const int*)d_in[3];    // [N, 16]
    const float* W              = (const float*)d_in[4];  // [256, 256]
    const float* b_lin          = (const float*)d_in[5];  // [256]
    const float* bias           = (const float*)d_in[6];  // [256]
    float* out = (float*)d_out;

    const int N = in_sizes[0] / D_DIM;   // 50000
    float* support = (float*)d_ws;       // N*256*4 = 51.2 MB scratch

    // Kernel 1: support = input @ W^T + b_lin
    dim3 g1((N + TM - 1) / TM, D_DIM / TN);
    gemm_support<<<g1, 256, 0, stream>>>(input_features, W, b_lin, support, N);

    // Kernel 2: message gather/reduce + tanh + bias
    const int nodes_per_block = 256 / 64;  // 4 waves per block
    dim3 g2((N + nodes_per_block - 1) / nodes_per_block);
    gather_msg<<<g2, 256, 0, stream>>>(support, fedges, a2a, n2e, bias, out, N);
}